// Round 3
// baseline (832.295 us; speedup 1.0000x reference)
//
#include <hip/hip_runtime.h>

// Net_23484881175023: conv1d(k=3,stride=3) -> LSTM(input=1, hidden=10, T=8192) -> Linear(10,3)
// B=512, L=24576, Lp=8192. One wave per batch element, lane = hid*4 + gate.
//
// R2 post-mortem: removing chain ops changed nothing => single-wave issue
// cadence (~4 cyc/instr) dominates: 227 cyc/step ~= 4 x ~45 VALU instrs.
// R3 strategy: MINIMIZE VALU INSTRUCTION COUNT PER STEP (~33):
//   - dot(h, W_hh) as 5 v_pk_fma_f32 (packed fp32, exact) with h-pairs in
//     SGPR pairs (10 v_readlane; the u64 packing is SALU = cadence-free).
//   - cell/h update uses quad_perm DPP broadcasts folded into VOP2 consumers
//     (cs/h are valid quad-replicated; lanes 40-63 and cross-quad values are
//     garbage-tolerant, never read).

#define DEV __device__ __forceinline__

typedef __attribute__((ext_vector_type(2))) float f32x2;

DEV int rl_i(float v, int lane) {
  return __builtin_amdgcn_readlane(__float_as_int(v), lane);
}
DEV float rl_f(float v, int lane) { return __int_as_float(rl_i(v, lane)); }

template <int CTRL>
DEV float quad_bcast(float v) {
#if __has_builtin(__builtin_amdgcn_mov_dpp)
  return __int_as_float(__builtin_amdgcn_mov_dpp(__float_as_int(v), CTRL, 0xF, 0xF, true));
#else
  return __int_as_float(__builtin_amdgcn_update_dpp(0, __float_as_int(v), CTRL, 0xF, 0xF, true));
#endif
}

DEV float fast_exp2(float x) {
#if __has_builtin(__builtin_amdgcn_exp2f)
  return __builtin_amdgcn_exp2f(x);
#else
  return __exp2f(x);
#endif
}

DEV float fast_rcp(float x) { return __builtin_amdgcn_rcpf(x); }

// d = a * b + c, elementwise on 2xfp32; b is a wave-uniform SGPR pair.
DEV f32x2 pk_fma_sb(f32x2 a, unsigned long long b, f32x2 c) {
  f32x2 d;
  asm("v_pk_fma_f32 %0, %1, %2, %3" : "=v"(d) : "v"(a), "s"(b), "v"(c));
  return d;
}
DEV f32x2 pk_mul_sb(f32x2 a, unsigned long long b) {
  f32x2 d;
  asm("v_pk_mul_f32 %0, %1, %2" : "=v"(d) : "v"(a), "s"(b));
  return d;
}

DEV unsigned long long pack2(int lo, int hi) {
  return (unsigned long long)(unsigned)lo | ((unsigned long long)(unsigned)hi << 32);
}

constexpr int kB = 512;
constexpr int kL = 24576;
constexpr int kLp = 8192;      // kL / 3
constexpr int kHid = 10;
constexpr int kChunk = 64;     // timesteps per chunk (one conv output per lane)
constexpr int kNChunk = kLp / kChunk;  // 128

__global__ __launch_bounds__(256, 1) void lstm_fused(
    const float* __restrict__ x,       // (B, L, 1)
    const float* __restrict__ conv_w,  // (1,1,3)
    const float* __restrict__ conv_b,  // (1,)
    const float* __restrict__ w_ih,    // (40,1)
    const float* __restrict__ w_hh,    // (40,10)
    const float* __restrict__ b_ih,    // (40,)
    const float* __restrict__ b_hh,    // (40,)
    const float* __restrict__ mlp_w,   // (3,10)
    const float* __restrict__ mlp_b,   // (3,)
    float* __restrict__ out) {         // (B,3)
  const int lane = threadIdx.x & 63;
  const int wave = threadIdx.x >> 6;
  const int b = blockIdx.x * 4 + wave;

  const int hid = lane >> 2;   // 0..9 for active lanes
  const int gt = lane & 3;     // 0:i 1:f 2:g 3:o (torch gate order)
  const bool active = (lane < 40);
  const int r = active ? (gt * kHid + hid) : 0;  // row in the 4H-stacked weights

  // uniform conv params (scalar loads)
  const float cw0 = conv_w[0], cw1 = conv_w[1], cw2 = conv_w[2];
  const float cbv = conv_b[0];

  constexpr float kL2E = 1.4426950408889634f;  // log2(e)
  constexpr float kSc = -2.0f * kL2E;          // cell-state exp-arg scale
  constexpr float kSc2 = 2.0f * kSc;           // -4*log2e
  constexpr float kScN = -kSc;                 // +2*log2e
  // gate g uses sigmoid(2x) (tanh folding); i/f/o use sigmoid(x).
  // smul (exp2-arg scale) is pre-folded into all dot inputs.
  const float smul = (gt == 2) ? (-2.0f * kL2E) : (-kL2E);

  // per-lane gate-row params, pre-scaled by smul; W as 5 packed fp32 pairs
  const float wih_s = w_ih[r] * smul;
  const float bsum_s = (b_ih[r] + b_hh[r]) * smul;
  const float* wr = w_hh + r * kHid;
  f32x2 wp0 = {wr[0] * smul, wr[1] * smul};
  f32x2 wp1 = {wr[2] * smul, wr[3] * smul};
  f32x2 wp2 = {wr[4] * smul, wr[5] * smul};
  f32x2 wp3 = {wr[6] * smul, wr[7] * smul};
  f32x2 wp4 = {wr[8] * smul, wr[9] * smul};

  const float* xb = x + (size_t)b * kL;
  const int xoff = lane * 3;

  // prefetch chunk 0's x values
  float x0 = xb[xoff + 0];
  float x1 = xb[xoff + 1];
  float x2 = xb[xoff + 2];

  float h = 0.0f;    // h[hid], valid quad-replicated
  float cs = 0.0f;   // kSc * c[hid], valid quad-replicated

  for (int ch = 0; ch < kNChunk; ++ch) {
    // conv output for timestep (ch*64 + lane), all 64 lanes
    float ct = fmaf(x2, cw2, fmaf(x1, cw1, fmaf(x0, cw0, cbv)));
    ct = fmaxf(ct, 0.0f);

    // prefetch next chunk (consumed after the 64-step inner loop)
    if (ch + 1 < kNChunk) {
      const float* xn = xb + (size_t)(ch + 1) * (kChunk * 3) + xoff;
      x0 = xn[0];
      x1 = xn[1];
      x2 = xn[2];
    }

#pragma unroll 16
    for (int t = 0; t < kChunk; ++t) {
      // input-side preactivation, pre-scaled (independent of h/cs; fills
      // cadence slots in the tanh-station shadow)
      const float ctv = rl_f(ct, t);
      const float xgs = fmaf(ctv, wih_s, bsum_s);

      // broadcast h via readlane -> 5 SGPR pairs (u64 packing is SALU)
      const unsigned long long hp0 = pack2(rl_i(h, 0), rl_i(h, 4));
      const unsigned long long hp1 = pack2(rl_i(h, 8), rl_i(h, 12));
      const unsigned long long hp2 = pack2(rl_i(h, 16), rl_i(h, 20));
      const unsigned long long hp3 = pack2(rl_i(h, 24), rl_i(h, 28));
      const unsigned long long hp4 = pack2(rl_i(h, 32), rl_i(h, 36));

      // ps = smul*(xg + dot(h, w_hh[r])): 5 packed ops + 2 adds
      f32x2 acc = pk_mul_sb(wp0, hp0);
      acc = pk_fma_sb(wp1, hp1, acc);
      acc = pk_fma_sb(wp2, hp2, acc);
      acc = pk_fma_sb(wp3, hp3, acc);
      acc = pk_fma_sb(wp4, hp4, acc);
      const float ps = (acc.x + acc.y) + xgs;

      // gate: a = sigmoid(pre) for i/f/o, sigmoid(2*pre) for g (scale folded)
      const float a = fast_rcp(1.0f + fast_exp2(ps));

      // cell update, quad-replicated via quad_perm DPP (foldable into VOP2):
      // cs' = fv*cs + kSc2*(iv*gv) + kScN*iv
      const float iv = quad_bcast<0x00>(a);
      const float gv = quad_bcast<0xAA>(a);
      const float m = gv * iv;
      const float tq = kScN * iv;
      const float us = fmaf(m, kSc2, tq);
      cs = fmaf(quad_bcast<0x55>(a), cs, us);

      // h = o*tanh(c) = ov*(2*sigmoid(2c)-1), sigmoid(2c) = rcp(1+exp2(cs))
      const float s2 = fast_rcp(1.0f + fast_exp2(cs));
      const float t3 = fmaf(s2, 2.0f, -1.0f);
      h = quad_bcast<0xFF>(a) * t3;
    }
  }

  // epilogue: out[b][m] = sum_k h[k]*mlp_w[m][k] + mlp_b[m], m = 0..2
  if (lane < 3) {
    const float* mw = mlp_w + lane * kHid;
    float acc = mlp_b[lane];
    acc = fmaf(rl_f(h, 0), mw[0], acc);
    acc = fmaf(rl_f(h, 4), mw[1], acc);
    acc = fmaf(rl_f(h, 8), mw[2], acc);
    acc = fmaf(rl_f(h, 12), mw[3], acc);
    acc = fmaf(rl_f(h, 16), mw[4], acc);
    acc = fmaf(rl_f(h, 20), mw[5], acc);
    acc = fmaf(rl_f(h, 24), mw[6], acc);
    acc = fmaf(rl_f(h, 28), mw[7], acc);
    acc = fmaf(rl_f(h, 32), mw[8], acc);
    acc = fmaf(rl_f(h, 36), mw[9], acc);
    out[b * 3 + lane] = acc;
  }
}

extern "C" void kernel_launch(void* const* d_in, const int* in_sizes, int n_in,
                              void* d_out, int out_size, void* d_ws, size_t ws_size,
                              hipStream_t stream) {
  const float* x = (const float*)d_in[0];
  const float* conv_w = (const float*)d_in[1];
  const float* conv_b = (const float*)d_in[2];
  const float* w_ih = (const float*)d_in[3];
  const float* w_hh = (const float*)d_in[4];
  const float* b_ih = (const float*)d_in[5];
  const float* b_hh = (const float*)d_in[6];
  const float* mlp_w = (const float*)d_in[7];
  const float* mlp_b = (const float*)d_in[8];
  float* out = (float*)d_out;

  // 128 blocks x 256 threads = 512 waves; one wave per batch element.
  dim3 grid(kB / 4), block(256);
  hipLaunchKernelGGL(lstm_fused, grid, block, 0, stream, x, conv_w, conv_b,
                     w_ih, w_hh, b_ih, b_hh, mlp_w, mlp_b, out);
}